// Round 6
// baseline (20.089 us; speedup 1.0000x reference)
//
#include <hip/hip_runtime.h>

#define B_   256
#define P_   1152
#define J_   10
#define NT   576      // 9 waves
#define ROWS 2        // p = w*128 + r*64 + lane
#define LOG2E 1.44269504088896340736f

// ---- DPP helpers (VALU pipe, no LDS) ----
template<int CTRL>
__device__ __forceinline__ float dpp_add(float v) {
  // v += dpp_mov<CTRL>(v); llvm fuses into v_add_f32_dpp
  int s = __builtin_amdgcn_update_dpp(0, __builtin_bit_cast(int, v), CTRL, 0xF, 0xF, true);
  return v + __builtin_bit_cast(float, s);
}
// row_shr 1,2,4,8: lane15 of each 16-lane row ends with the row sum
__device__ __forceinline__ float rsum_shr(float v) {
  v = dpp_add<0x111>(v); v = dpp_add<0x112>(v);
  v = dpp_add<0x114>(v); v = dpp_add<0x118>(v);
  return v;
}
// row_ror 1,2,4,8: ALL 16 lanes of the row end with the row sum
__device__ __forceinline__ float rsum_ror(float v) {
  v = dpp_add<0x121>(v); v = dpp_add<0x122>(v);
  v = dpp_add<0x124>(v); v = dpp_add<0x128>(v);
  return v;
}

// LDS (static, ~19.7 KB):
//  ypart [36][92]  per-16-lane-group partials (cols 0..79 y[j][k]@j*8+k, 80..89 e-sums)
//  Wt    [80][18]  Wt[(j*8+k)*18+d] = W[j][d][k]
//  red   [92]      reduced y[80] + S[10]
//  Zacc  [80]      cumulative z * log2(e)
__global__ __launch_bounds__(NT, 4) void caps_kernel(const float* __restrict__ x,
                                                     const float* __restrict__ Wg,
                                                     float* __restrict__ out) {
  __shared__ float ypart[36 * 92];
  __shared__ float Wt[80 * 18];
  __shared__ float red[92];
  __shared__ float Zacc[80];

  const int tid  = threadIdx.x;
  const int w    = tid >> 6;
  const int lane = tid & 63;
  const int b    = blockIdx.x;

  // ---- preamble: x rows -> registers, W -> Wt (transposed) ----
  float xr[ROWS][8];
  {
    const float* xb = x + ((size_t)b * P_ + w * 128 + lane) * 8;
    #pragma unroll
    for (int r = 0; r < ROWS; ++r) {
      const float4 a = *reinterpret_cast<const float4*>(xb + r * 64 * 8);
      const float4 c = *reinterpret_cast<const float4*>(xb + r * 64 * 8 + 4);
      xr[r][0] = a.x; xr[r][1] = a.y; xr[r][2] = a.z; xr[r][3] = a.w;
      xr[r][4] = c.x; xr[r][5] = c.y; xr[r][6] = c.z; xr[r][7] = c.w;
    }
  }
  for (int t = tid; t < J_ * 16 * 8; t += NT) {
    const int j = t >> 7, d = (t >> 3) & 15, k = t & 7;
    Wt[(j * 8 + k) * 18 + d] = Wg[t];
  }
  __syncthreads();

  for (int it = 0; it < 3; ++it) {
    // ---------------- Y phase: registers + DPP, j-split for VGPR diet ----------------
    if (it == 0) {                        // e == 1: y[k] = colsum(x), S = P
      float cs[8];
      #pragma unroll
      for (int k = 0; k < 8; ++k) cs[k] = rsum_shr(xr[0][k] + xr[1][k]);
      if ((lane & 15) == 15) {
        const int row = w * 4 + (lane >> 4);
        *reinterpret_cast<float4*>(&ypart[row * 92 + 0]) = make_float4(cs[0], cs[1], cs[2], cs[3]);
        *reinterpret_cast<float4*>(&ypart[row * 92 + 4]) = make_float4(cs[4], cs[5], cs[6], cs[7]);
      }
    } else {
      #pragma unroll
      for (int jh = 0; jh < 2; ++jh) {
        float acc[5][8], accs[5];
        #pragma unroll
        for (int j5 = 0; j5 < 5; ++j5) {
          accs[j5] = 0.f;
          #pragma unroll
          for (int k = 0; k < 8; ++k) acc[j5][k] = 0.f;
        }
        #pragma unroll
        for (int j5 = 0; j5 < 5; ++j5) {
          const int j = jh * 5 + j5;
          const float4 z0 = *reinterpret_cast<const float4*>(&Zacc[j * 8]);
          const float4 z1 = *reinterpret_cast<const float4*>(&Zacc[j * 8 + 4]);
          #pragma unroll
          for (int r = 0; r < ROWS; ++r) {
            float t = xr[r][0] * z0.x;
            t = fmaf(xr[r][1], z0.y, t);
            t = fmaf(xr[r][2], z0.z, t);
            t = fmaf(xr[r][3], z0.w, t);
            t = fmaf(xr[r][4], z1.x, t);
            t = fmaf(xr[r][5], z1.y, t);
            t = fmaf(xr[r][6], z1.z, t);
            t = fmaf(xr[r][7], z1.w, t);
            const float e = exp2f(t);     // Zacc pre-scaled by log2(e)
            accs[j5] += e;
            #pragma unroll
            for (int k = 0; k < 8; ++k) acc[j5][k] = fmaf(e, xr[r][k], acc[j5][k]);
          }
        }
        #pragma unroll
        for (int j5 = 0; j5 < 5; ++j5) {  // DPP reduce (VALU pipe)
          #pragma unroll
          for (int k = 0; k < 8; ++k) acc[j5][k] = rsum_shr(acc[j5][k]);
          accs[j5] = rsum_shr(accs[j5]);
        }
        if ((lane & 15) == 15) {
          const int row = w * 4 + (lane >> 4);
          float* rp = &ypart[row * 92];
          #pragma unroll
          for (int j5 = 0; j5 < 5; ++j5) {
            *reinterpret_cast<float4*>(rp + jh * 40 + j5 * 8)     = make_float4(acc[j5][0], acc[j5][1], acc[j5][2], acc[j5][3]);
            *reinterpret_cast<float4*>(rp + jh * 40 + j5 * 8 + 4) = make_float4(acc[j5][4], acc[j5][5], acc[j5][6], acc[j5][7]);
            rp[80 + jh * 5 + j5] = accs[j5];
          }
        }
      }
    }
    __syncthreads();

    // ---------------- M_A: combine 36 group-partials ----------------
    if (tid < ((it == 0) ? 8 : 90)) {
      float s0 = 0.f, s1 = 0.f, s2 = 0.f, s3 = 0.f;
      #pragma unroll
      for (int r = 0; r < 36; r += 4) {
        s0 += ypart[(r    ) * 92 + tid];
        s1 += ypart[(r + 1) * 92 + tid];
        s2 += ypart[(r + 2) * 92 + tid];
        s3 += ypart[(r + 3) * 92 + tid];
      }
      red[tid] = (s0 + s1) + (s2 + s3);
    }
    __syncthreads();

    // ---------------- M_B(+C): s -> squash -> v -> (out | z -> Zacc) ----------------
    if (tid < 160) {
      const int j = tid >> 4, d = tid & 15;
      const int yb = (it == 0) ? 0 : j * 8;
      const float Ss = (it == 0) ? (float)P_ : red[80 + j];
      float wk[8];
      #pragma unroll
      for (int k = 0; k < 8; ++k) wk[k] = Wt[(j * 8 + k) * 18 + d];
      float s = 0.f;
      #pragma unroll
      for (int k = 0; k < 8; ++k) s = fmaf(wk[k], red[yb + k], s);
      s /= Ss;
      const float sq = rsum_ror(s * s);           // all 16 lanes get ||s||^2
      const float scal = sq / ((1.0f + sq) * sqrtf(sq + 1e-9f));
      const float v = s * scal;
      if (it == 2) {
        out[b * 160 + tid] = v;
      } else {
        // z[j][k] = sum_d W[j][d][k] * v_d via 16-lane DPP shr; lane15 holds all 8
        float zk[8];
        #pragma unroll
        for (int k = 0; k < 8; ++k) zk[k] = rsum_shr(wk[k] * v);
        if (d == 15) {
          float* zp = &Zacc[j * 8];
          if (it == 0) {
            #pragma unroll
            for (int k = 0; k < 8; ++k) zp[k] = zk[k] * LOG2E;
          } else {
            #pragma unroll
            for (int k = 0; k < 8; ++k) zp[k] = fmaf(zk[k], LOG2E, zp[k]);
          }
        }
      }
    }
    if (it < 2) __syncthreads();
  }
}

extern "C" void kernel_launch(void* const* d_in, const int* in_sizes, int n_in,
                              void* d_out, int out_size, void* d_ws, size_t ws_size,
                              hipStream_t stream) {
  (void)in_sizes; (void)n_in; (void)out_size; (void)d_ws; (void)ws_size;
  const float* x = (const float*)d_in[0];
  const float* W = (const float*)d_in[1];
  float* out = (float*)d_out;
  caps_kernel<<<B_, NT, 0, stream>>>(x, W, out);
}

// Round 7
// 15.530 us; speedup vs baseline: 1.2935x; 1.2935x over previous
//
#include <hip/hip_runtime.h>

#define B_   256
#define P_   1152
#define J_   10
#define NT   384      // 6 waves
#define NWV  6
#define PW   192      // p-rows per wave
#define LOG2E 1.44269504088896340736f

typedef __attribute__((ext_vector_type(8))) short short8;
typedef __attribute__((ext_vector_type(4))) float f32x4;

union Frag { short8 s; unsigned u[4]; };

__device__ __forceinline__ unsigned pk_bf16(float lo, float hi) {
  unsigned r;
  asm("v_cvt_pk_bf16_f32 %0, %1, %2" : "=v"(r) : "v"(lo), "v"(hi));
  return r;
}
__device__ __forceinline__ float bf_lo(unsigned u){ return __builtin_bit_cast(float, u << 16); }
__device__ __forceinline__ float bf_hi(unsigned u){ return __builtin_bit_cast(float, u & 0xffff0000u); }

template<int CTRL>
__device__ __forceinline__ float dpp_add(float v) {
  int s = __builtin_amdgcn_update_dpp(0, __builtin_bit_cast(int, v), CTRL, 0xF, 0xF, true);
  return v + __builtin_bit_cast(float, s);
}
__device__ __forceinline__ float rsum_shr(float v) {  // lane15 of 16-row gets sum
  v = dpp_add<0x111>(v); v = dpp_add<0x112>(v);
  v = dpp_add<0x114>(v); v = dpp_add<0x118>(v);
  return v;
}
__device__ __forceinline__ float rsum_ror(float v) {  // all 16 lanes get sum
  v = dpp_add<0x121>(v); v = dpp_add<0x122>(v);
  v = dpp_add<0x124>(v); v = dpp_add<0x128>(v);
  return v;
}

// LDS (dynamic, 88944 B):
//  xT    short[16][1168] @0      x^T in bf16: rows 0-7 = x[k][p], row 8 = ones (S-col), 9-15 zero
//  eL    short[6][16][200] @37376  per-wave e (bf16), [j][p_loc] rows
//  Wt    float[80*18]   @75776   Wt[(j*8+k)*18+d] = W[j][d][k]
//  ypart float[6][272]  @81536   per-wave y tiles [16j][17k-pad]
//  red   float[92]      @88064   y[j*8+k], S at 80+j
//  Zacc  float[128]     @88432   cumulative z*log2e (rows 80-127 stay 0)
__global__ __launch_bounds__(NT, 2) void caps_kernel(const float* __restrict__ x,
                                                     const float* __restrict__ Wg,
                                                     float* __restrict__ out) {
  extern __shared__ char smc[];
  short* xT    = (short*)smc;
  short* eL    = (short*)(smc + 37376);
  float* Wt    = (float*)(smc + 75776);
  float* ypart = (float*)(smc + 81536);
  float* red   = (float*)(smc + 88064);
  float* Zacc  = (float*)(smc + 88432);

  const int tid  = threadIdx.x;
  const int w    = tid >> 6;
  const int lane = tid & 63;
  const int b    = blockIdx.x;
  const int jl   = lane & 15;     // 16-col index (j or k depending on phase)
  const int g    = lane >> 4;     // 4-group

  // ---- phase 0: zero xT + Zacc ----
  {
    float4* xTf = (float4*)xT;
    const float4 z4 = make_float4(0.f, 0.f, 0.f, 0.f);
    for (int i = tid; i < 2336; i += NT) xTf[i] = z4;
    if (tid < 128) Zacc[tid] = 0.f;
  }
  __syncthreads();

  // ---- phase 1: fill xT (bf16, transposed + ones row), Wt; build A-frags from global ----
  const float* xb = x + (size_t)b * (P_ * 8);
  for (int i = tid; i < 2304; i += NT) {
    float4 v4 = ((const float4*)xb)[i];
    const int p = i >> 1, k0 = (i & 1) * 4;
    xT[(k0 + 0) * 1168 + p] = (short)(pk_bf16(v4.x, v4.x) & 0xffff);
    xT[(k0 + 1) * 1168 + p] = (short)(pk_bf16(v4.y, v4.y) & 0xffff);
    xT[(k0 + 2) * 1168 + p] = (short)(pk_bf16(v4.z, v4.z) & 0xffff);
    xT[(k0 + 3) * 1168 + p] = (short)(pk_bf16(v4.w, v4.w) & 0xffff);
  }
  for (int p = tid; p < P_; p += NT) xT[8 * 1168 + p] = (short)0x3F80;
  for (int t = tid; t < 1280; t += NT) {
    const int j = t >> 7, d = (t >> 3) & 15, k = t & 7;
    Wt[(j * 8 + k) * 18 + d] = Wg[t];
  }

  // A-frags for the b-matmul: x row p=16t+jl; groups 0,2 hold xh, 1,3 hold xl
  Frag Ax[12];
  {
    const bool lop = (g & 1);
    #pragma unroll
    for (int t = 0; t < 12; ++t) {
      const float* xr = xb + ((size_t)(w * PW + t * 16 + jl)) * 8;
      const float4 a4 = ((const float4*)xr)[0];
      const float4 b4 = ((const float4*)xr)[1];
      const float xv[8] = {a4.x, a4.y, a4.z, a4.w, b4.x, b4.y, b4.z, b4.w};
      #pragma unroll
      for (int q = 0; q < 4; ++q) {
        unsigned h = pk_bf16(xv[2 * q], xv[2 * q + 1]);
        if (lop) {
          const float l0 = xv[2 * q]     - bf_lo(h);
          const float l1 = xv[2 * q + 1] - bf_hi(h);
          h = pk_bf16(l0, l1);
        }
        Ax[t].u[q] = h;
      }
    }
  }
  __syncthreads();

  // B-frags for the y-matmul (iteration-invariant): col=jl, 8 consecutive p from xT
  Frag Bx[6];
  #pragma unroll
  for (int tp = 0; tp < 6; ++tp)
    Bx[tp].s = *(const short8*)&xT[jl * 1168 + w * PW + tp * 32 + g * 8];

  Frag ones;
  #pragma unroll
  for (int q = 0; q < 4; ++q) ones.u[q] = 0x3F803F80u;

  for (int it = 0; it < 3; ++it) {
    // ---------------- Y phase: b-MFMA -> exp2 -> y-MFMA ----------------
    f32x4 yC = {0.f, 0.f, 0.f, 0.f};
    if (it == 0) {                      // e == 1 everywhere
      #pragma unroll
      for (int tp = 0; tp < 6; ++tp)
        yC = __builtin_amdgcn_mfma_f32_16x16x32_bf16(ones.s, Bx[tp].s, yC, 0, 0, 0);
    } else {
      Frag zf;                          // B-frag of Z: rows 0-15 Zh, 16-31 Zl
      {
        const float4 za = *(const float4*)&Zacc[jl * 8];
        const float4 zb = *(const float4*)&Zacc[jl * 8 + 4];
        const float zv[8] = {za.x, za.y, za.z, za.w, zb.x, zb.y, zb.z, zb.w};
        #pragma unroll
        for (int q = 0; q < 4; ++q) {
          unsigned h = pk_bf16(zv[2 * q], zv[2 * q + 1]);
          if (g >= 2) {
            const float l0 = zv[2 * q]     - bf_lo(h);
            const float l1 = zv[2 * q + 1] - bf_hi(h);
            h = pk_bf16(l0, l1);
          }
          zf.u[q] = h;
        }
      }
      short* eW = eL + w * 3200;
      #pragma unroll
      for (int t = 0; t < 12; ++t) {    // b = x.Z exactly (hi/lo packed in K)
        f32x4 bC = {0.f, 0.f, 0.f, 0.f};
        bC = __builtin_amdgcn_mfma_f32_16x16x32_bf16(Ax[t].s, zf.s, bC, 0, 0, 0);
        const float e0 = exp2f(bC[0]), e1 = exp2f(bC[1]);
        const float e2 = exp2f(bC[2]), e3 = exp2f(bC[3]);
        *(uint2*)&eW[jl * 200 + t * 16 + g * 4] =
            make_uint2(pk_bf16(e0, e1), pk_bf16(e2, e3));
      }
      #pragma unroll
      for (int tp = 0; tp < 6; ++tp) {  // y[j][k] (+ S at col 8) over this wave's p
        Frag af;
        af.s = *(const short8*)&eW[jl * 200 + tp * 32 + g * 8];
        yC = __builtin_amdgcn_mfma_f32_16x16x32_bf16(af.s, Bx[tp].s, yC, 0, 0, 0);
      }
    }
    #pragma unroll
    for (int r = 0; r < 4; ++r)         // D[j=g*4+r][k=jl]
      ypart[w * 272 + (g * 4 + r) * 17 + jl] = yC[r];
    __syncthreads();

    // ---------------- M_A: combine 6 wave partials ----------------
    if (tid < 160) {
      const int j = tid >> 4, k = tid & 15;
      if (k < 9) {
        float s = 0.f;
        #pragma unroll
        for (int w6 = 0; w6 < NWV; ++w6) s += ypart[w6 * 272 + j * 17 + k];
        red[(k < 8) ? (j * 8 + k) : (80 + j)] = s;
      }
    }
    __syncthreads();

    // ---------------- M_B(+C): s -> squash -> v -> (out | z -> Zacc) ----------------
    if (tid < 160) {
      const int j = tid >> 4, d = tid & 15;
      float wk[8];
      #pragma unroll
      for (int k = 0; k < 8; ++k) wk[k] = Wt[(j * 8 + k) * 18 + d];
      float s = 0.f;
      #pragma unroll
      for (int k = 0; k < 8; ++k) s = fmaf(wk[k], red[j * 8 + k], s);
      s /= red[80 + j];
      const float sq = rsum_ror(s * s);
      const float scal = sq / ((1.0f + sq) * sqrtf(sq + 1e-9f));
      const float v = s * scal;
      if (it == 2) {
        out[b * 160 + tid] = v;
      } else {
        float zk[8];
        #pragma unroll
        for (int k = 0; k < 8; ++k) zk[k] = rsum_shr(wk[k] * v);
        if (d == 15) {
          #pragma unroll
          for (int k = 0; k < 8; ++k)
            Zacc[j * 8 + k] = fmaf(zk[k], LOG2E, Zacc[j * 8 + k]);
        }
      }
    }
    if (it < 2) __syncthreads();
  }
}

extern "C" void kernel_launch(void* const* d_in, const int* in_sizes, int n_in,
                              void* d_out, int out_size, void* d_ws, size_t ws_size,
                              hipStream_t stream) {
  (void)in_sizes; (void)n_in; (void)out_size; (void)d_ws; (void)ws_size;
  const float* x = (const float*)d_in[0];
  const float* W = (const float*)d_in[1];
  float* out = (float*)d_out;

  const size_t smem = 88944;
  (void)hipFuncSetAttribute(reinterpret_cast<const void*>(caps_kernel),
                            hipFuncAttributeMaxDynamicSharedMemorySize, (int)smem);
  caps_kernel<<<B_, NT, smem, stream>>>(x, W, out);
}